// Round 6
// baseline (304.867 us; speedup 1.0000x reference)
//
#include <hip/hip_runtime.h>
#include <math.h>

// CRF loss: B=256, L=256, T=50.
// R16: R15 with the fwd fold FIXED (R15 contracted the wrong index: it
//   computed P.x instead of x.P; restored to R14's verified wave-0 form:
//   xv[J] = x[16J+n], p[I][r] = sum_J xv[J]*d[J][I][r], reduce over n,
//   n==0 writes x_lds[16I+4q+r]).
// Structure (R15): 16 segments/batch, driven by the measured "~115 cy per
//   serial MFMA per wave" law (R10=116, R12=123, R13=105, R14=123 cy/MFMA).
//   512 blocks (batch x dir) x 8 waves: wave w owns a 16-step segment.
//   fwd block: right-mult P <- (P.E2).diag(eh)  (R14-verified STEPM).
//   bwd block: left-mult Q <- E2.(diag(eh).Q) at descending l = eh-PRE-
//   scaled B pack + bwd-orientation A-frags; state d[J][I][r] =
//   Q[16I+4q+r][16J+n] keeps the recurrence lane-local.
//   Folds: no LDS matrices — each wave keeps its segment product in regs;
//   8 serial folds pass a 64-float vector via LDS (barrier each):
//     fwd: y[16I+4q+r] = sum_row x[row].P[row][16I+4q+r] (reduce over n)
//     bwd: x'[16I+4q+r] = sum_col Q[16I+4q+r][col].x[col] (reduce over n)
//   u/w/Sf/Sb -> ws; combine kernel unchanged (R10/R13-verbatim).
//   eh streams from global (R14 LOADG incl. offset-46 I=3 trick), 1 step
//   ahead; fwd wave7's 16th step (l=128) is gated off.

#define TAGS 50
#define LEN 256
#define NB 256
#define TOTF (NB * LEN * TAGS)
#define INV_LN2 1.4426950408889634f
#define LN2 0.6931471805599453f

typedef __attribute__((ext_vector_type(8))) short bf16x8;
typedef __attribute__((ext_vector_type(4))) float f32x4;
typedef __attribute__((ext_vector_type(4), aligned(4))) float f32x4u;

#if __has_builtin(__builtin_amdgcn_exp2f)
#define EXP2F(x) __builtin_amdgcn_exp2f(x)
#else
#define EXP2F(x) exp2f(x)
#endif
#if __has_builtin(__builtin_amdgcn_logf)
#define LOG2F(x) __builtin_amdgcn_logf(x)
#else
#define LOG2F(x) log2f(x)
#endif
#if __has_builtin(__builtin_amdgcn_rcpf)
#define RCPF(x) __builtin_amdgcn_rcpf(x)
#else
#define RCPF(x) (1.0f / (x))
#endif

__device__ __forceinline__ float readlane_f(float v, int srclane) {
  return __builtin_bit_cast(float,
      __builtin_amdgcn_readlane(__builtin_bit_cast(int, v), srclane));
}

__device__ __forceinline__ int bf16pairInit(float lo, float hi) {
  unsigned lb = (__builtin_bit_cast(unsigned, lo) + 0x8000u) >> 16;
  unsigned hb = (__builtin_bit_cast(unsigned, hi) + 0x8000u) & 0xFFFF0000u;
  return (int)(hb | lb);
}

// One-instruction pack: dst = (bf16(hi)<<16) | bf16(lo), RNE.
#define PACK2(dst, lo, hi) \
  asm("v_cvt_pk_bf16_f32 %0, %1, %2" : "=v"(dst) : "v"(lo), "v"(hi))

union U8 { int i[4]; bf16x8 v; };

// ws layout (floats): u[NB][64] | w[NB][64] | Sf[NB] | Sb[NB]
#define WS_U(b)  ((b) * 64)
#define WS_W(b)  ((NB + (b)) * 64)
#define WS_SF(b) (2 * NB * 64 + (b))
#define WS_SB(b) (2 * NB * 64 + NB + (b))

__global__ __launch_bounds__(512, 4) void crf_seg_kernel(
    const float* __restrict__ feats,   // (B, L, T)
    const float* __restrict__ trans,   // (T, T)
    const int*   __restrict__ mask,    // (B, L)
    float*       __restrict__ ws)
{
  const int bid    = blockIdx.x;
  const bool is_fwd = bid < NB;
  const int b      = is_fwd ? bid : bid - NB;
  const int tid    = threadIdx.x;
  const int w      = tid >> 6;
  const int lane   = tid & 63;
  const int q      = lane >> 4;
  const int n      = lane & 15;

  __shared__ __align__(16) float x_lds[64];
  __shared__ float Sseg[8];

  // ---- mask ballots (wave-uniform SGPRs; identical in every wave) ----
  const int* mbp = mask + b * LEN;
  const unsigned long long mb0 = __ballot(mbp[lane] > 0);
  const unsigned long long mb1 = __ballot(mbp[64 + lane] > 0);
  const unsigned long long mb2 = __ballot(mbp[128 + lane] > 0);
  const unsigned long long mb3 = __ballot(mbp[192 + lane] > 0);
#define MASKBIT(L)                                                          \
  ((int)(((((L) & 128) ? (((L) & 64) ? mb3 : mb2)                           \
                       : (((L) & 64) ? mb1 : mb0)) >> ((L) & 63)) & 1ull))

  // ---- Constant A-frags: fwd = E2^T orientation (R14), bwd = E2 rows ----
  U8 Afr[4][2];
#pragma unroll
  for (int t = 0; t < 4; ++t)
#pragma unroll
    for (int c = 0; c < 2; ++c)
#pragma unroll
      for (int r = 0; r < 4; ++r) {
        const int col = 16 * t + n;
        const int tag0 = 16 * c + 4 * q + r;
        const int tag1 = tag0 + 32;
        float e0 = 0.0f, e1 = 0.0f;
        if (col < TAGS) {
          if (tag0 < TAGS)
            e0 = EXP2F((is_fwd ? trans[tag0 * TAGS + col]
                               : trans[col * TAGS + tag0]) * INV_LN2);
          if (tag1 < TAGS)
            e1 = EXP2F((is_fwd ? trans[tag1 * TAGS + col]
                               : trans[col * TAGS + tag1]) * INV_LN2);
        }
        Afr[t][c].i[r] = bf16pairInit(e0, e1);
      }

  const f32x4 zero4 = {0.0f, 0.0f, 0.0f, 0.0f};

  // State init P = I (identical expression for both layouts).
  f32x4 d[4][4];
#pragma unroll
  for (int J = 0; J < 4; ++J)
#pragma unroll
    for (int I = 0; I < 4; ++I)
#pragma unroll
      for (int r = 0; r < 4; ++r)
        d[J][I][r] = (16 * J + n == 16 * I + 4 * q + r) ? 1.0f : 0.0f;

  float S = 0.0f;
  f32x4u rA[4], rB[4];

#define LOADG(BK, L) do {                                                   \
    const float* _p = feats + (size_t)b * (LEN * TAGS) + (size_t)(L) * TAGS;\
    BK[0] = *(const f32x4u*)(_p + 4 * q);                                   \
    BK[1] = *(const f32x4u*)(_p + 16 + 4 * q);                              \
    BK[2] = *(const f32x4u*)(_p + 32 + 4 * q);                              \
    const float* _p3 = _p + 46 + 4 * q;                                     \
    const float* _lim = feats + (TOTF - 4);                                 \
    if (_p3 > _lim) _p3 = _lim;                                             \
    BK[3] = *(const f32x4u*)_p3;                                            \
  } while (0)

#define RENORMM() do {                                                      \
    const float _cc = readlane_f(d[0][0][0], 0);                            \
    const float _rr = RCPF(_cc);                                            \
    S += LOG2F(_cc);                                                        \
    _Pragma("unroll") for (int _J = 0; _J < 4; ++_J)                        \
    _Pragma("unroll") for (int _I = 0; _I < 4; ++_I)                        \
    _Pragma("unroll") for (int _r = 0; _r < 4; ++_r)                        \
      d[_J][_I][_r] *= _rr;                                                 \
  } while (0)

  // ev from raw EH (R14's I=3 trick: only q=0,r<2 matter; junk lands on
  // structurally-zero rows/cols).
#define MKEV(EH)                                                            \
    float ev[4][4];                                                         \
    _Pragma("unroll") for (int _i = 0; _i < 3; ++_i)                        \
    _Pragma("unroll") for (int _r = 0; _r < 4; ++_r)                        \
      ev[_i][_r] = EXP2F(EH[_i][_r] * INV_LN2);                             \
    ev[3][0] = EXP2F(EH[3][2] * INV_LN2);                                   \
    ev[3][1] = EXP2F(EH[3][3] * INV_LN2);                                   \
    ev[3][2] = 0.0f; ev[3][3] = 0.0f

#define MFMA8J(B0_, B1_)                                                    \
    f32x4 t0 = __builtin_amdgcn_mfma_f32_16x16x32_bf16(Afr[0][1].v, B1_.v, zero4, 0, 0, 0); \
    f32x4 t1 = __builtin_amdgcn_mfma_f32_16x16x32_bf16(Afr[1][1].v, B1_.v, zero4, 0, 0, 0); \
    f32x4 t2 = __builtin_amdgcn_mfma_f32_16x16x32_bf16(Afr[2][1].v, B1_.v, zero4, 0, 0, 0); \
    f32x4 t3 = __builtin_amdgcn_mfma_f32_16x16x32_bf16(Afr[3][1].v, B1_.v, zero4, 0, 0, 0); \
    t0 = __builtin_amdgcn_mfma_f32_16x16x32_bf16(Afr[0][0].v, B0_.v, t0, 0, 0, 0); \
    t1 = __builtin_amdgcn_mfma_f32_16x16x32_bf16(Afr[1][0].v, B0_.v, t1, 0, 0, 0); \
    t2 = __builtin_amdgcn_mfma_f32_16x16x32_bf16(Afr[2][0].v, B0_.v, t2, 0, 0, 0); \
    t3 = __builtin_amdgcn_mfma_f32_16x16x32_bf16(Afr[3][0].v, B0_.v, t3, 0, 0, 0)

  // fwd: P <- (P.E2) col-scaled (R14 STEPM verbatim + l<=127 gate).
#define STEPF(EH, L) do {                                                   \
    if ((L) <= 127 && MASKBIT(L)) {                                         \
      MKEV(EH);                                                             \
      _Pragma("unroll") for (int _J = 0; _J < 4; ++_J) {                    \
        U8 B0, B1;                                                          \
        _Pragma("unroll") for (int _r = 0; _r < 4; ++_r) {                  \
          PACK2(B0.i[_r], d[_J][0][_r], d[_J][2][_r]);                      \
          PACK2(B1.i[_r], d[_J][1][_r], d[_J][3][_r]);                      \
        }                                                                   \
        MFMA8J(B0, B1);                                                     \
        _Pragma("unroll") for (int _r = 0; _r < 4; ++_r) {                  \
          d[_J][0][_r] = t0[_r] * ev[0][_r];                                \
          d[_J][1][_r] = t1[_r] * ev[1][_r];                                \
          d[_J][2][_r] = t2[_r] * ev[2][_r];                                \
          d[_J][3][_r] = t3[_r] * ev[3][_r];                                \
        }                                                                   \
      }                                                                     \
    }                                                                       \
  } while (0)

  // bwd: Q <- E2.(diag(eh).Q): eh PRE-scales the B K-slots (rows of Q).
#define STEPB(EH, L) do {                                                   \
    if (MASKBIT(L)) {                                                       \
      MKEV(EH);                                                             \
      _Pragma("unroll") for (int _J = 0; _J < 4; ++_J) {                    \
        U8 B0, B1;                                                          \
        _Pragma("unroll") for (int _r = 0; _r < 4; ++_r) {                  \
          PACK2(B0.i[_r], ev[0][_r] * d[_J][0][_r], ev[2][_r] * d[_J][2][_r]); \
          PACK2(B1.i[_r], ev[1][_r] * d[_J][1][_r], ev[3][_r] * d[_J][3][_r]); \
        }                                                                   \
        MFMA8J(B0, B1);                                                     \
        _Pragma("unroll") for (int _r = 0; _r < 4; ++_r) {                  \
          d[_J][0][_r] = t0[_r];                                            \
          d[_J][1][_r] = t1[_r];                                            \
          d[_J][2][_r] = t2[_r];                                            \
          d[_J][3][_r] = t3[_r];                                            \
        }                                                                   \
      }                                                                     \
    }                                                                       \
  } while (0)

  // ---- Segment scan: 16 steps/wave (fwd wave7's 16th is gated off) ----
  if (is_fwd) {
    int l = 1 + 16 * w;
    LOADG(rA, l);
    LOADG(rB, l + 1);
    for (int kk = 0; kk < 8; ++kk) {
      if ((kk & 1) == 0) RENORMM();
      STEPF(rA, l); LOADG(rA, l + 2);
      ++l;
      STEPF(rB, l); LOADG(rB, l + 2);
      ++l;
    }
  } else {
    int l = 143 + 16 * w;
    LOADG(rA, l);
    LOADG(rB, l - 1);
    for (int kk = 0; kk < 8; ++kk) {
      if ((kk & 1) == 0) RENORMM();
      STEPB(rA, l); LOADG(rA, l - 2);
      --l;
      STEPB(rB, l); LOADG(rB, l - 2);
      --l;
    }
  }

  __syncthreads();

  // ---- Folds: pass x through LDS, 8 serial rounds, P stays in regs ----
  if (is_fwd) {
    // y = x . P : contract over P's row index (16J+n), reduce over n.
    // (R14-verified wave-0 epilogue form; R15's q-contraction was the bug.)
    for (int f = 0; f < 8; ++f) {
      if (w == f) {
        float xv[4];
        if (f == 0) {
#pragma unroll
          for (int J = 0; J < 4; ++J) {
            const int tg = 16 * J + n;
            xv[J] = (tg < TAGS)
                        ? EXP2F(feats[(size_t)b * (LEN * TAGS) + tg] * INV_LN2)
                        : 0.0f;
          }
        } else {
#pragma unroll
          for (int J = 0; J < 4; ++J) xv[J] = x_lds[16 * J + n];
        }
        float p[4][4];
#pragma unroll
        for (int I = 0; I < 4; ++I)
#pragma unroll
          for (int r = 0; r < 4; ++r)
            p[I][r] = xv[0] * d[0][I][r] + xv[1] * d[1][I][r] +
                      xv[2] * d[2][I][r] + xv[3] * d[3][I][r];
#pragma unroll
        for (int off = 1; off <= 8; off <<= 1)
#pragma unroll
          for (int I = 0; I < 4; ++I)
#pragma unroll
            for (int r = 0; r < 4; ++r)
              p[I][r] += __shfl_xor(p[I][r], off, 64);
        const float cc = readlane_f(p[0][0], 0);
        const float rr = RCPF(cc);
        S += LOG2F(cc);
        if (n == 0) {
#pragma unroll
          for (int I = 0; I < 4; ++I)
#pragma unroll
            for (int r = 0; r < 4; ++r)
              x_lds[16 * I + 4 * q + r] = p[I][r] * rr;
        }
        if (lane == 0) Sseg[w] = S;
      }
      __syncthreads();
    }
    if (tid < 64) ws[WS_U(b) + tid] = x_lds[tid];
    if (tid == 0) {
      float s = 0.0f;
#pragma unroll
      for (int i = 0; i < 8; ++i) s += Sseg[i];
      ws[WS_SF(b)] = s;
    }
  } else {
    // x' = Q . x : contract over Q's col index (16J+n), reduce over n.
    for (int f2 = 0; f2 < 8; ++f2) {
      if (w == 7 - f2) {
        float xv[4];
        if (w == 7) {
#pragma unroll
          for (int J = 0; J < 4; ++J) xv[J] = (16 * J + n < TAGS) ? 1.0f : 0.0f;
        } else {
#pragma unroll
          for (int J = 0; J < 4; ++J) xv[J] = x_lds[16 * J + n];
        }
        float t[4][4];
#pragma unroll
        for (int I = 0; I < 4; ++I)
#pragma unroll
          for (int r = 0; r < 4; ++r)
            t[I][r] = xv[0] * d[0][I][r] + xv[1] * d[1][I][r] +
                      xv[2] * d[2][I][r] + xv[3] * d[3][I][r];
#pragma unroll
        for (int off = 1; off <= 8; off <<= 1)
#pragma unroll
          for (int I = 0; I < 4; ++I)
#pragma unroll
            for (int r = 0; r < 4; ++r)
              t[I][r] += __shfl_xor(t[I][r], off, 64);
        const float cc = readlane_f(t[0][0], 0);
        const float rr = RCPF(cc);
        S += LOG2F(cc);
        if (n == 0) {
#pragma unroll
          for (int I = 0; I < 4; ++I)
#pragma unroll
            for (int r = 0; r < 4; ++r)
              x_lds[16 * I + 4 * q + r] = t[I][r] * rr;
        }
        if (lane == 0) Sseg[w] = S;
      }
      __syncthreads();
    }
    if (tid < 64) ws[WS_W(b) + tid] = x_lds[tid];
    if (tid == 0) {
      float s = 0.0f;
#pragma unroll
      for (int i = 0; i < 8; ++i) s += Sseg[i];
      ws[WS_SB(b)] = s;
    }
  }
#undef MASKBIT
#undef LOADG
#undef RENORMM
#undef MKEV
#undef MFMA8J
#undef STEPF
#undef STEPB
}

__global__ __launch_bounds__(64) void crf_combine_kernel(
    const float* __restrict__ feats,   // (B, L, T)
    const float* __restrict__ trans,   // (T, T)
    const int*   __restrict__ tags,    // (B, L)
    const int*   __restrict__ mask,    // (B, L)
    const float* __restrict__ ws,
    float*       __restrict__ out)     // (B,)
{
  const int b = blockIdx.x;
  const int lane = threadIdx.x;

  // normalizer = ln2 * (Sf + Sb + log2(sum_tag u*w))   (pads are 0)
  float s = ws[WS_U(b) + lane] * ws[WS_W(b) + lane];
#pragma unroll
  for (int off = 32; off; off >>= 1) s += __shfl_xor(s, off, 64);

  // gold score: lane handles positions lane, +64, +128, +192
  const float* fb = feats + (size_t)b * (LEN * TAGS);
  const int*   tb = tags + b * LEN;
  const int*   mb = mask + b * LEN;
  float gp = 0.0f;
#pragma unroll
  for (int k = 0; k < 4; ++k) {
    const int p = lane + 64 * k;
    const int tg = tb[p];
    if (mb[p] > 0) {
      float vv = fb[p * TAGS + tg];
      if (p >= 1) vv += trans[tb[p - 1] * TAGS + tg];
      gp += vv;
    }
  }
#pragma unroll
  for (int off = 32; off; off >>= 1) gp += __shfl_xor(gp, off, 64);

  if (lane == 0) {
    const float Sf = ws[WS_SF(b)];
    const float Sb = ws[WS_SB(b)];
    out[b] = LN2 * (Sf + Sb + LOG2F(s)) - gp;
  }
}

extern "C" void kernel_launch(void* const* d_in, const int* in_sizes, int n_in,
                              void* d_out, int out_size, void* d_ws, size_t ws_size,
                              hipStream_t stream) {
  const float* feats = (const float*)d_in[0];
  const float* trans = (const float*)d_in[1];
  const int*   tags  = (const int*)d_in[2];
  const int*   mask  = (const int*)d_in[3];
  float* out = (float*)d_out;
  float* ws  = (float*)d_ws;   // needs (2*256*64 + 512) * 4 = 133 KB

  crf_seg_kernel<<<2 * NB, 512, 0, stream>>>(feats, trans, mask, ws);
  crf_combine_kernel<<<NB, 64, 0, stream>>>(feats, trans, tags, mask, ws, out);
}

// Round 7
// 126.484 us; speedup vs baseline: 2.4103x; 2.4103x over previous
//
#include <hip/hip_runtime.h>
#include <math.h>

// CRF loss: B=256, L=256, T=50.
// R17: R16 with ONE change — __launch_bounds__(512,4) -> (512,1).
//   R16 PASSED correctness (16-segment structure + bwd left-mult algebra +
//   fixed fwd fold are all harness-verified) but the (512,4) bound squeezed
//   the unified VGPR/AGPR budget to 64 arch VGPRs (R14: 88 for the same
//   state) -> the d[4][4] f32x4 accumulators spilled to scratch:
//   FETCH 263MB / WRITE 455MB per dispatch (R14: 6.8MB/8KB), 243us.
//   (512,1) is R14's proven setting: 88 VGPR, no spill, 2 blocks/CU.
// Structure (R15/R16): 16 segments/batch, driven by the measured "~115 cy
//   per serial MFMA per wave" law (R10=116, R12=123, R13=105, R14=123).
//   512 blocks (batch x dir) x 8 waves: wave w owns a 16-step segment.
//   fwd block: right-mult P <- (P.E2).diag(eh)  (R14-verified STEPM).
//   bwd block: left-mult Q <- E2.(diag(eh).Q) at descending l = eh-PRE-
//   scaled B pack + bwd-orientation A-frags; state d[J][I][r] =
//   Q[16I+4q+r][16J+n] keeps the recurrence lane-local.
//   Folds: no LDS matrices — each wave keeps its segment product in regs;
//   8 serial folds pass a 64-float vector via LDS (barrier each):
//     fwd: y[16I+4q+r] = sum_row x[row].P[row][16I+4q+r] (reduce over n)
//     bwd: x'[16I+4q+r] = sum_col Q[16I+4q+r][col].x[col] (reduce over n)
//   u/w/Sf/Sb -> ws; combine kernel unchanged (R10/R13-verbatim).
//   eh streams from global (R14 LOADG incl. offset-46 I=3 trick), 1 step
//   ahead; fwd wave7's 16th step (l=128) is gated off.

#define TAGS 50
#define LEN 256
#define NB 256
#define TOTF (NB * LEN * TAGS)
#define INV_LN2 1.4426950408889634f
#define LN2 0.6931471805599453f

typedef __attribute__((ext_vector_type(8))) short bf16x8;
typedef __attribute__((ext_vector_type(4))) float f32x4;
typedef __attribute__((ext_vector_type(4), aligned(4))) float f32x4u;

#if __has_builtin(__builtin_amdgcn_exp2f)
#define EXP2F(x) __builtin_amdgcn_exp2f(x)
#else
#define EXP2F(x) exp2f(x)
#endif
#if __has_builtin(__builtin_amdgcn_logf)
#define LOG2F(x) __builtin_amdgcn_logf(x)
#else
#define LOG2F(x) log2f(x)
#endif
#if __has_builtin(__builtin_amdgcn_rcpf)
#define RCPF(x) __builtin_amdgcn_rcpf(x)
#else
#define RCPF(x) (1.0f / (x))
#endif

__device__ __forceinline__ float readlane_f(float v, int srclane) {
  return __builtin_bit_cast(float,
      __builtin_amdgcn_readlane(__builtin_bit_cast(int, v), srclane));
}

__device__ __forceinline__ int bf16pairInit(float lo, float hi) {
  unsigned lb = (__builtin_bit_cast(unsigned, lo) + 0x8000u) >> 16;
  unsigned hb = (__builtin_bit_cast(unsigned, hi) + 0x8000u) & 0xFFFF0000u;
  return (int)(hb | lb);
}

// One-instruction pack: dst = (bf16(hi)<<16) | bf16(lo), RNE.
#define PACK2(dst, lo, hi) \
  asm("v_cvt_pk_bf16_f32 %0, %1, %2" : "=v"(dst) : "v"(lo), "v"(hi))

union U8 { int i[4]; bf16x8 v; };

// ws layout (floats): u[NB][64] | w[NB][64] | Sf[NB] | Sb[NB]
#define WS_U(b)  ((b) * 64)
#define WS_W(b)  ((NB + (b)) * 64)
#define WS_SF(b) (2 * NB * 64 + (b))
#define WS_SB(b) (2 * NB * 64 + NB + (b))

__global__ __launch_bounds__(512, 1) void crf_seg_kernel(
    const float* __restrict__ feats,   // (B, L, T)
    const float* __restrict__ trans,   // (T, T)
    const int*   __restrict__ mask,    // (B, L)
    float*       __restrict__ ws)
{
  const int bid    = blockIdx.x;
  const bool is_fwd = bid < NB;
  const int b      = is_fwd ? bid : bid - NB;
  const int tid    = threadIdx.x;
  const int w      = tid >> 6;
  const int lane   = tid & 63;
  const int q      = lane >> 4;
  const int n      = lane & 15;

  __shared__ __align__(16) float x_lds[64];
  __shared__ float Sseg[8];

  // ---- mask ballots (wave-uniform SGPRs; identical in every wave) ----
  const int* mbp = mask + b * LEN;
  const unsigned long long mb0 = __ballot(mbp[lane] > 0);
  const unsigned long long mb1 = __ballot(mbp[64 + lane] > 0);
  const unsigned long long mb2 = __ballot(mbp[128 + lane] > 0);
  const unsigned long long mb3 = __ballot(mbp[192 + lane] > 0);
#define MASKBIT(L)                                                          \
  ((int)(((((L) & 128) ? (((L) & 64) ? mb3 : mb2)                           \
                       : (((L) & 64) ? mb1 : mb0)) >> ((L) & 63)) & 1ull))

  // ---- Constant A-frags: fwd = E2^T orientation (R14), bwd = E2 rows ----
  U8 Afr[4][2];
#pragma unroll
  for (int t = 0; t < 4; ++t)
#pragma unroll
    for (int c = 0; c < 2; ++c)
#pragma unroll
      for (int r = 0; r < 4; ++r) {
        const int col = 16 * t + n;
        const int tag0 = 16 * c + 4 * q + r;
        const int tag1 = tag0 + 32;
        float e0 = 0.0f, e1 = 0.0f;
        if (col < TAGS) {
          if (tag0 < TAGS)
            e0 = EXP2F((is_fwd ? trans[tag0 * TAGS + col]
                               : trans[col * TAGS + tag0]) * INV_LN2);
          if (tag1 < TAGS)
            e1 = EXP2F((is_fwd ? trans[tag1 * TAGS + col]
                               : trans[col * TAGS + tag1]) * INV_LN2);
        }
        Afr[t][c].i[r] = bf16pairInit(e0, e1);
      }

  const f32x4 zero4 = {0.0f, 0.0f, 0.0f, 0.0f};

  // State init P = I (identical expression for both layouts).
  f32x4 d[4][4];
#pragma unroll
  for (int J = 0; J < 4; ++J)
#pragma unroll
    for (int I = 0; I < 4; ++I)
#pragma unroll
      for (int r = 0; r < 4; ++r)
        d[J][I][r] = (16 * J + n == 16 * I + 4 * q + r) ? 1.0f : 0.0f;

  float S = 0.0f;
  f32x4u rA[4], rB[4];

#define LOADG(BK, L) do {                                                   \
    const float* _p = feats + (size_t)b * (LEN * TAGS) + (size_t)(L) * TAGS;\
    BK[0] = *(const f32x4u*)(_p + 4 * q);                                   \
    BK[1] = *(const f32x4u*)(_p + 16 + 4 * q);                              \
    BK[2] = *(const f32x4u*)(_p + 32 + 4 * q);                              \
    const float* _p3 = _p + 46 + 4 * q;                                     \
    const float* _lim = feats + (TOTF - 4);                                 \
    if (_p3 > _lim) _p3 = _lim;                                             \
    BK[3] = *(const f32x4u*)_p3;                                            \
  } while (0)

#define RENORMM() do {                                                      \
    const float _cc = readlane_f(d[0][0][0], 0);                            \
    const float _rr = RCPF(_cc);                                            \
    S += LOG2F(_cc);                                                        \
    _Pragma("unroll") for (int _J = 0; _J < 4; ++_J)                        \
    _Pragma("unroll") for (int _I = 0; _I < 4; ++_I)                        \
    _Pragma("unroll") for (int _r = 0; _r < 4; ++_r)                        \
      d[_J][_I][_r] *= _rr;                                                 \
  } while (0)

  // ev from raw EH (R14's I=3 trick: only q=0,r<2 matter; junk lands on
  // structurally-zero rows/cols).
#define MKEV(EH)                                                            \
    float ev[4][4];                                                         \
    _Pragma("unroll") for (int _i = 0; _i < 3; ++_i)                        \
    _Pragma("unroll") for (int _r = 0; _r < 4; ++_r)                        \
      ev[_i][_r] = EXP2F(EH[_i][_r] * INV_LN2);                             \
    ev[3][0] = EXP2F(EH[3][2] * INV_LN2);                                   \
    ev[3][1] = EXP2F(EH[3][3] * INV_LN2);                                   \
    ev[3][2] = 0.0f; ev[3][3] = 0.0f

#define MFMA8J(B0_, B1_)                                                    \
    f32x4 t0 = __builtin_amdgcn_mfma_f32_16x16x32_bf16(Afr[0][1].v, B1_.v, zero4, 0, 0, 0); \
    f32x4 t1 = __builtin_amdgcn_mfma_f32_16x16x32_bf16(Afr[1][1].v, B1_.v, zero4, 0, 0, 0); \
    f32x4 t2 = __builtin_amdgcn_mfma_f32_16x16x32_bf16(Afr[2][1].v, B1_.v, zero4, 0, 0, 0); \
    f32x4 t3 = __builtin_amdgcn_mfma_f32_16x16x32_bf16(Afr[3][1].v, B1_.v, zero4, 0, 0, 0); \
    t0 = __builtin_amdgcn_mfma_f32_16x16x32_bf16(Afr[0][0].v, B0_.v, t0, 0, 0, 0); \
    t1 = __builtin_amdgcn_mfma_f32_16x16x32_bf16(Afr[1][0].v, B0_.v, t1, 0, 0, 0); \
    t2 = __builtin_amdgcn_mfma_f32_16x16x32_bf16(Afr[2][0].v, B0_.v, t2, 0, 0, 0); \
    t3 = __builtin_amdgcn_mfma_f32_16x16x32_bf16(Afr[3][0].v, B0_.v, t3, 0, 0, 0)

  // fwd: P <- (P.E2) col-scaled (R14 STEPM verbatim + l<=127 gate).
#define STEPF(EH, L) do {                                                   \
    if ((L) <= 127 && MASKBIT(L)) {                                         \
      MKEV(EH);                                                             \
      _Pragma("unroll") for (int _J = 0; _J < 4; ++_J) {                    \
        U8 B0, B1;                                                          \
        _Pragma("unroll") for (int _r = 0; _r < 4; ++_r) {                  \
          PACK2(B0.i[_r], d[_J][0][_r], d[_J][2][_r]);                      \
          PACK2(B1.i[_r], d[_J][1][_r], d[_J][3][_r]);                      \
        }                                                                   \
        MFMA8J(B0, B1);                                                     \
        _Pragma("unroll") for (int _r = 0; _r < 4; ++_r) {                  \
          d[_J][0][_r] = t0[_r] * ev[0][_r];                                \
          d[_J][1][_r] = t1[_r] * ev[1][_r];                                \
          d[_J][2][_r] = t2[_r] * ev[2][_r];                                \
          d[_J][3][_r] = t3[_r] * ev[3][_r];                                \
        }                                                                   \
      }                                                                     \
    }                                                                       \
  } while (0)

  // bwd: Q <- E2.(diag(eh).Q): eh PRE-scales the B K-slots (rows of Q).
#define STEPB(EH, L) do {                                                   \
    if (MASKBIT(L)) {                                                       \
      MKEV(EH);                                                             \
      _Pragma("unroll") for (int _J = 0; _J < 4; ++_J) {                    \
        U8 B0, B1;                                                          \
        _Pragma("unroll") for (int _r = 0; _r < 4; ++_r) {                  \
          PACK2(B0.i[_r], ev[0][_r] * d[_J][0][_r], ev[2][_r] * d[_J][2][_r]); \
          PACK2(B1.i[_r], ev[1][_r] * d[_J][1][_r], ev[3][_r] * d[_J][3][_r]); \
        }                                                                   \
        MFMA8J(B0, B1);                                                     \
        _Pragma("unroll") for (int _r = 0; _r < 4; ++_r) {                  \
          d[_J][0][_r] = t0[_r];                                            \
          d[_J][1][_r] = t1[_r];                                            \
          d[_J][2][_r] = t2[_r];                                            \
          d[_J][3][_r] = t3[_r];                                            \
        }                                                                   \
      }                                                                     \
    }                                                                       \
  } while (0)

  // ---- Segment scan: 16 steps/wave (fwd wave7's 16th is gated off) ----
  if (is_fwd) {
    int l = 1 + 16 * w;
    LOADG(rA, l);
    LOADG(rB, l + 1);
    for (int kk = 0; kk < 8; ++kk) {
      if ((kk & 1) == 0) RENORMM();
      STEPF(rA, l); LOADG(rA, l + 2);
      ++l;
      STEPF(rB, l); LOADG(rB, l + 2);
      ++l;
    }
  } else {
    int l = 143 + 16 * w;
    LOADG(rA, l);
    LOADG(rB, l - 1);
    for (int kk = 0; kk < 8; ++kk) {
      if ((kk & 1) == 0) RENORMM();
      STEPB(rA, l); LOADG(rA, l - 2);
      --l;
      STEPB(rB, l); LOADG(rB, l - 2);
      --l;
    }
  }

  __syncthreads();

  // ---- Folds: pass x through LDS, 8 serial rounds, P stays in regs ----
  if (is_fwd) {
    // y = x . P : contract over P's row index (16J+n), reduce over n.
    for (int f = 0; f < 8; ++f) {
      if (w == f) {
        float xv[4];
        if (f == 0) {
#pragma unroll
          for (int J = 0; J < 4; ++J) {
            const int tg = 16 * J + n;
            xv[J] = (tg < TAGS)
                        ? EXP2F(feats[(size_t)b * (LEN * TAGS) + tg] * INV_LN2)
                        : 0.0f;
          }
        } else {
#pragma unroll
          for (int J = 0; J < 4; ++J) xv[J] = x_lds[16 * J + n];
        }
        float p[4][4];
#pragma unroll
        for (int I = 0; I < 4; ++I)
#pragma unroll
          for (int r = 0; r < 4; ++r)
            p[I][r] = xv[0] * d[0][I][r] + xv[1] * d[1][I][r] +
                      xv[2] * d[2][I][r] + xv[3] * d[3][I][r];
#pragma unroll
        for (int off = 1; off <= 8; off <<= 1)
#pragma unroll
          for (int I = 0; I < 4; ++I)
#pragma unroll
            for (int r = 0; r < 4; ++r)
              p[I][r] += __shfl_xor(p[I][r], off, 64);
        const float cc = readlane_f(p[0][0], 0);
        const float rr = RCPF(cc);
        S += LOG2F(cc);
        if (n == 0) {
#pragma unroll
          for (int I = 0; I < 4; ++I)
#pragma unroll
            for (int r = 0; r < 4; ++r)
              x_lds[16 * I + 4 * q + r] = p[I][r] * rr;
        }
        if (lane == 0) Sseg[w] = S;
      }
      __syncthreads();
    }
    if (tid < 64) ws[WS_U(b) + tid] = x_lds[tid];
    if (tid == 0) {
      float s = 0.0f;
#pragma unroll
      for (int i = 0; i < 8; ++i) s += Sseg[i];
      ws[WS_SF(b)] = s;
    }
  } else {
    // x' = Q . x : contract over Q's col index (16J+n), reduce over n.
    for (int f2 = 0; f2 < 8; ++f2) {
      if (w == 7 - f2) {
        float xv[4];
        if (w == 7) {
#pragma unroll
          for (int J = 0; J < 4; ++J) xv[J] = (16 * J + n < TAGS) ? 1.0f : 0.0f;
        } else {
#pragma unroll
          for (int J = 0; J < 4; ++J) xv[J] = x_lds[16 * J + n];
        }
        float t[4][4];
#pragma unroll
        for (int I = 0; I < 4; ++I)
#pragma unroll
          for (int r = 0; r < 4; ++r)
            t[I][r] = xv[0] * d[0][I][r] + xv[1] * d[1][I][r] +
                      xv[2] * d[2][I][r] + xv[3] * d[3][I][r];
#pragma unroll
        for (int off = 1; off <= 8; off <<= 1)
#pragma unroll
          for (int I = 0; I < 4; ++I)
#pragma unroll
            for (int r = 0; r < 4; ++r)
              t[I][r] += __shfl_xor(t[I][r], off, 64);
        const float cc = readlane_f(t[0][0], 0);
        const float rr = RCPF(cc);
        S += LOG2F(cc);
        if (n == 0) {
#pragma unroll
          for (int I = 0; I < 4; ++I)
#pragma unroll
            for (int r = 0; r < 4; ++r)
              x_lds[16 * I + 4 * q + r] = t[I][r] * rr;
        }
        if (lane == 0) Sseg[w] = S;
      }
      __syncthreads();
    }
    if (tid < 64) ws[WS_W(b) + tid] = x_lds[tid];
    if (tid == 0) {
      float s = 0.0f;
#pragma unroll
      for (int i = 0; i < 8; ++i) s += Sseg[i];
      ws[WS_SB(b)] = s;
    }
  }
#undef MASKBIT
#undef LOADG
#undef RENORMM
#undef MKEV
#undef MFMA8J
#undef STEPF
#undef STEPB
}

__global__ __launch_bounds__(64) void crf_combine_kernel(
    const float* __restrict__ feats,   // (B, L, T)
    const float* __restrict__ trans,   // (T, T)
    const int*   __restrict__ tags,    // (B, L)
    const int*   __restrict__ mask,    // (B, L)
    const float* __restrict__ ws,
    float*       __restrict__ out)     // (B,)
{
  const int b = blockIdx.x;
  const int lane = threadIdx.x;

  // normalizer = ln2 * (Sf + Sb + log2(sum_tag u*w))   (pads are 0)
  float s = ws[WS_U(b) + lane] * ws[WS_W(b) + lane];
#pragma unroll
  for (int off = 32; off; off >>= 1) s += __shfl_xor(s, off, 64);

  // gold score: lane handles positions lane, +64, +128, +192
  const float* fb = feats + (size_t)b * (LEN * TAGS);
  const int*   tb = tags + b * LEN;
  const int*   mb = mask + b * LEN;
  float gp = 0.0f;
#pragma unroll
  for (int k = 0; k < 4; ++k) {
    const int p = lane + 64 * k;
    const int tg = tb[p];
    if (mb[p] > 0) {
      float vv = fb[p * TAGS + tg];
      if (p >= 1) vv += trans[tb[p - 1] * TAGS + tg];
      gp += vv;
    }
  }
#pragma unroll
  for (int off = 32; off; off >>= 1) gp += __shfl_xor(gp, off, 64);

  if (lane == 0) {
    const float Sf = ws[WS_SF(b)];
    const float Sb = ws[WS_SB(b)];
    out[b] = LN2 * (Sf + Sb + LOG2F(s)) - gp;
  }
}

extern "C" void kernel_launch(void* const* d_in, const int* in_sizes, int n_in,
                              void* d_out, int out_size, void* d_ws, size_t ws_size,
                              hipStream_t stream) {
  const float* feats = (const float*)d_in[0];
  const float* trans = (const float*)d_in[1];
  const int*   tags  = (const int*)d_in[2];
  const int*   mask  = (const int*)d_in[3];
  float* out = (float*)d_out;
  float* ws  = (float*)d_ws;   // needs (2*256*64 + 512) * 4 = 133 KB

  crf_seg_kernel<<<2 * NB, 512, 0, stream>>>(feats, trans, mask, ws);
  crf_combine_kernel<<<NB, 64, 0, stream>>>(feats, trans, tags, mask, ws, out);
}